// Round 11
// baseline (124.171 us; speedup 1.0000x reference)
//
#include <hip/hip_runtime.h>

#define BS 4096
#define LL 512
#define NCH 16                // 16 chunks of 32 steps; wave owns 4 chains
#define CS 32
#define START_TAG 1
#define END_TAG 2
#define BIASF 4.5f            // per-applied-step 2^-BIASF scaling (restored exactly)
#define L2E 1.44269504f

typedef float f32x4 __attribute__((ext_vector_type(4)));
typedef short s16x4 __attribute__((ext_vector_type(4)));
union BF4 { unsigned u[2]; s16x4 s; };

__device__ __forceinline__ unsigned cvt_pk_bf16(float lo, float hi) {
    unsigned r;
    asm("v_cvt_pk_bf16_f32 %0, %1, %2" : "=v"(r) : "v"(lo), "v"(hi));
    return r;
}
__device__ __forceinline__ float blo(unsigned u) { return __uint_as_float(u << 16); }
__device__ __forceinline__ float bhi(unsigned u) { return __uint_as_float(u & 0xFFFF0000u); }

#define RENX(P01, P23, E2F) { \
        const float v0 = blo(P01), v1 = bhi(P01), v2 = blo(P23), v3 = bhi(P23); \
        float mm = fmaxf(fmaxf(v0, v1), fmaxf(v2, v3)); \
        _Pragma("unroll") \
        for (int o = 1; o <= 32; o <<= 1) mm = fmaxf(mm, __shfl_xor(mm, o)); \
        if (mm > 0.f) { \
            const int ex = (int)((__float_as_uint(mm) >> 23) & 0xFFu) - 127; \
            const float sre = __uint_as_float((unsigned)(127 - ex) << 23); \
            E2F += (float)ex; \
            P01 = cvt_pk_bf16(v0 * sre, v1 * sre); \
            P23 = cvt_pk_bf16(v2 * sre, v3 * sre); } }

// Block = one batch, 4 waves; wave wv owns FOUR 32-step chunks (4wv..4wv+3) as
// interleaved independent MFMA chains with software-pipelined LDS reads:
//   M_c = prod_{t active} diag(e^{em_t} 2^-BIASF) * E^T     (E = exp(tr))
// Scales mask-compacted at staging; fully-unrolled fast path when all active.
__global__ __launch_bounds__(256, 3) void crf_quad(
    const float* __restrict__ em, const int* __restrict__ tg,
    const float* __restrict__ mk, const float* __restrict__ tr,
    float* __restrict__ out)
{
    __shared__ float sE[LL * 16];        // 32 KB compacted f32 scales
    __shared__ float sP[NCH][16][16];    // 16 KB chunk matrices
    __shared__ float sO[NCH];
    __shared__ float sSc[4], sCnt[4];

    const int tid  = threadIdx.x;
    const int wv   = tid >> 6;
    const int lane = tid & 63;
    const int j    = lane & 15;
    const int q    = lane >> 4;
    const long bb  = (long)blockIdx.x * LL;
    const int  t0  = wv * 128;           // this wave's 128 steps (4 chunks)

    // tags dtype detect (validated): 16 u64 words all <16 => int64 layout
    int is64 = 1;
    {
        const unsigned long long* t64 = (const unsigned long long*)tg;
#pragma unroll
        for (int i = 0; i < 16; ++i) is64 &= (t64[i] < 16ull) ? 1 : 0;
    }
    const int esz = is64 ? 2 : 1;

    // ---- mask ballots: lane = step within each 64-step half ----
    const float ml0 = mk[bb + t0 + lane];
    const float ml1 = mk[bb + t0 + 64 + lane];
    const unsigned long long bal0 = __ballot(ml0 > 0.f);
    const unsigned long long bal1 = __ballot(ml1 > 0.f);
    const unsigned bc0 = (unsigned)bal0, bc1 = (unsigned)(bal0 >> 32);
    const unsigned bc2 = (unsigned)bal1, bc3 = (unsigned)(bal1 >> 32);
    const int n0 = __popc(bc0), n1 = __popc(bc1), n2 = __popc(bc2), n3 = __popc(bc3);

    // ---- staging: coalesced em -> exp2 -> mask-compacted f32 scales ----
    {
        const float* emb = em + ((bb + t0) << 4);
        const unsigned bcs[4] = {bc0, bc1, bc2, bc3};
#pragma unroll
        for (int k = 0; k < 8; ++k) {
            const int idx = (lane << 2) + (k << 8);   // float idx in wave region
            const f32x4 v = *(const f32x4*)(emb + idx);
            const int st = idx >> 4;                  // step 0..127 (wave-local)
            const int rg = lane & 3;
            f32x4 e;
            e.x = exp2f(fmaf(v.x, L2E, -BIASF));
            e.y = exp2f(fmaf(v.y, L2E, -BIASF));
            e.z = exp2f(fmaf(v.z, L2E, -BIASF));
            e.w = exp2f(fmaf(v.w, L2E, -BIASF));
            const int ch = k >> 1;                    // compile-time per k
            const int stl = st & 31;
            const unsigned bm = bcs[ch];
            if ((bm >> stl) & 1u) {
                const int slot = __popc(bm & ((1u << stl) - 1u));
                *(f32x4*)(sE + (4 * wv + ch) * (CS * 16) + slot * 16 + rg * 4) = e;
            }
        }
    }

    // ---- path score + mask count: 2 steps per lane (L1-hot gathers) ----
    {
        float part = 0.f;
        {
            const int t    = t0 + lane;
            const int tcur = tg[(bb + t) * esz];
            const int tpv  = (t == 0) ? START_TAG : (int)tg[(bb + t - 1) * esz];
            const float scm = (t == 0) ? 1.f : ml0;
            part = fmaf(em[((bb + t) << 4) + tcur] + tr[tpv * 16 + tcur], scm, part);
        }
        {
            const int t    = t0 + 64 + lane;
            const int tcur = tg[(bb + t) * esz];
            const int tpv  = (int)tg[(bb + t - 1) * esz];
            part = fmaf(em[((bb + t) << 4) + tcur] + tr[tpv * 16 + tcur], ml1, part);
        }
        float cpart = ml0 + ml1;
#pragma unroll
        for (int o = 1; o <= 32; o <<= 1) {
            part  += __shfl_xor(part, o);
            cpart += __shfl_xor(cpart, o);
        }
        if (lane == 0) { sSc[wv] = part; sCnt[wv] = cpart; }
    }

    // ---- static A = E^T: lane (j,q) holds A[j][4q+i] = exp(tr[4q+i][j]) ----
    BF4 Ab;
    {
        float Ef[4];
#pragma unroll
        for (int i = 0; i < 4; ++i)
            Ef[i] = exp2f(tr[(q * 4 + i) * 16 + j] * L2E);  // exp(-1000) -> 0
        Ab.u[0] = cvt_pk_bf16(Ef[0], Ef[1]);
        Ab.u[1] = cvt_pk_bf16(Ef[2], Ef[3]);
    }

    // ---- 4 interleaved chains, software-pipelined LDS reads ----
    const unsigned idlo = ((q*4+0 == j) ? 0x3F80u : 0u) | (((q*4+1 == j) ? 0x3F80u : 0u) << 16);
    const unsigned idhi = ((q*4+2 == j) ? 0x3F80u : 0u) | (((q*4+3 == j) ? 0x3F80u : 0u) << 16);
    unsigned p01[4], p23[4];
    float e2f[4];
#pragma unroll
    for (int c = 0; c < 4; ++c) { p01[c] = idlo; p23[c] = idhi; e2f[c] = 0.f; }
    const float* pE0 = sE + (4 * wv) * (CS * 16) + (q << 2);

    if (n0 == CS && n1 == CS && n2 == CS && n3 == CS) {
        // fast path: fully unrolled, loads one step ahead of use
        f32x4 cur[4], nxt[4];
#pragma unroll
        for (int c = 0; c < 4; ++c) cur[c] = *(const f32x4*)(pE0 + c * (CS * 16));
#pragma unroll
        for (int i = 0; i < CS; ++i) {
            if (i + 1 < CS) {
#pragma unroll
                for (int c = 0; c < 4; ++c)
                    nxt[c] = *(const f32x4*)(pE0 + c * (CS * 16) + (i + 1) * 16);
            }
#pragma unroll
            for (int c = 0; c < 4; ++c) {
                BF4 Bf; Bf.u[0] = p01[c]; Bf.u[1] = p23[c];
                f32x4 z = {0.f, 0.f, 0.f, 0.f};
                f32x4 d = __builtin_amdgcn_mfma_f32_16x16x16bf16_1k(Ab.s, Bf.s, z, 0, 0, 0);
                p01[c] = cvt_pk_bf16(d[0] * cur[c].x, d[1] * cur[c].y);
                p23[c] = cvt_pk_bf16(d[2] * cur[c].z, d[3] * cur[c].w);
            }
            if (i + 1 < CS) {
#pragma unroll
                for (int c = 0; c < 4; ++c) cur[c] = nxt[c];
            }
            if (i == 15) {
#pragma unroll
                for (int c = 0; c < 4; ++c) RENX(p01[c], p23[c], e2f[c])
            }
        }
    } else {
        // generic path: per-chain runtime-bound loops (rare)
        const int nn[4] = {n0, n1, n2, n3};
#pragma unroll
        for (int c = 0; c < 4; ++c) {
            const float* pc = pE0 + c * (CS * 16);
            unsigned a01 = p01[c], a23 = p23[c];
            float ee = 0.f;
            for (int i = 0; i < nn[c]; ++i) {
                const f32x4 s4 = *(const f32x4*)(pc + i * 16);
                BF4 Bf; Bf.u[0] = a01; Bf.u[1] = a23;
                f32x4 z = {0.f, 0.f, 0.f, 0.f};
                f32x4 d = __builtin_amdgcn_mfma_f32_16x16x16bf16_1k(Ab.s, Bf.s, z, 0, 0, 0);
                a01 = cvt_pk_bf16(d[0] * s4.x, d[1] * s4.y);
                a23 = cvt_pk_bf16(d[2] * s4.z, d[3] * s4.w);
                if ((i & 15) == 15) RENX(a01, a23, ee)
            }
            p01[c] = a01; p23[c] = a23; e2f[c] = ee;
        }
    }

    // ---- chunk matrices -> LDS ----
#pragma unroll
    for (int c = 0; c < 4; ++c) {
        sP[4*wv+c][q*4+0][j] = blo(p01[c]);
        sP[4*wv+c][q*4+1][j] = bhi(p01[c]);
        sP[4*wv+c][q*4+2][j] = blo(p23[c]);
        sP[4*wv+c][q*4+3][j] = bhi(p23[c]);
    }
    if (lane == 0) {
#pragma unroll
        for (int c = 0; c < 4; ++c) sO[4*wv+c] = e2f[c];
    }
    __syncthreads();

    // ---- combine on lanes 0..15: alpha = M15*...*M0 * ones ----
    if (tid < 16) {
        const int jj = tid;
        float w = 1.f, l2 = 0.f;
#pragma unroll
        for (int c = 0; c < NCH; ++c) {
            float nw = 0.f;
#pragma unroll
            for (int i2 = 0; i2 < 16; ++i2)
                nw = fmaf(sP[c][jj][i2], __shfl(w, i2, 16), nw);
            float m = nw;
#pragma unroll
            for (int o = 1; o <= 8; o <<= 1) m = fmaxf(m, __shfl_xor(m, o, 16));
            m = fmaxf(m, 1e-30f);
            l2 += log2f(m);
            w = nw / m;
        }
        float scT = 0.f, cntT = 0.f, ot = 0.f;
#pragma unroll
        for (int c = 0; c < 4; ++c) { scT += sSc[c]; cntT += sCnt[c]; }
#pragma unroll
        for (int c = 0; c < NCH; ++c) ot += sO[c];
        ot += BIASF * cntT;

        float y = log2f(w) + l2 + ot + tr[jj * 16 + END_TAG] * L2E;
        float m2 = y;
#pragma unroll
        for (int o = 1; o <= 8; o <<= 1) m2 = fmaxf(m2, __shfl_xor(m2, o, 16));
        m2 = fmaxf(m2, -1e30f);
        float e = exp2f(y - m2);
#pragma unroll
        for (int o = 1; o <= 8; o <<= 1) e += __shfl_xor(e, o, 16);
        const float dp = (m2 + log2f(e)) * 0.69314718055994531f;

        if (jj == 0) {
            const int li = (int)cntT - 1;
            const int lt = tg[(bb + li) * esz];
            atomicAdd(out, dp - (scT + tr[lt * 16 + END_TAG]));
        }
    }
}

extern "C" void kernel_launch(void* const* d_in, const int* in_sizes, int n_in,
                              void* d_out, int out_size, void* d_ws, size_t ws_size,
                              hipStream_t stream) {
    const float* em = (const float*)d_in[0];
    const int*   tg = (const int*)d_in[1];
    const float* mk = (const float*)d_in[2];
    const float* tr = (const float*)d_in[3];
    float* out = (float*)d_out;

    hipMemsetAsync(out, 0, sizeof(float), stream);
    crf_quad<<<BS, 256, 0, stream>>>(em, tg, mk, tr, out);
}

// Round 13
// 79.214 us; speedup vs baseline: 1.5675x; 1.5675x over previous
//
#include <hip/hip_runtime.h>

#define BS 4096
#define LL 512
#define NW 8                  // waves per block = chunks per batch-group
#define SS 64                 // own steps per chunk
#define WU 16                 // warm-up steps for chunks c>=1 (contraction ~0.1^16)
#define NB 16                 // batches per block (= MFMA columns)
#define START_TAG 1
#define END_TAG 2
#define BIASF 4.5f            // per-applied-step 2^-BIASF (restored exactly in log2)
#define L2E 1.44269504f
#define LN2 0.69314718055994531f

typedef float f32x4 __attribute__((ext_vector_type(4)));
typedef short s16x4 __attribute__((ext_vector_type(4)));
union BF4 { unsigned u[2]; s16x4 s; };

__device__ __forceinline__ unsigned cvt_pk_bf16(float lo, float hi) {
    unsigned r;
    asm("v_cvt_pk_bf16_f32 %0, %1, %2" : "=v"(r) : "v"(lo), "v"(hi));
    return r;
}
__device__ __forceinline__ float blo(unsigned u) { return __uint_as_float(u << 16); }
__device__ __forceinline__ float bhi(unsigned u) { return __uint_as_float(u & 0xFFFF0000u); }

// Vec-mode CRF with warm-up chunk chaining (fwd-only, no transpose, no duality).
// Block = 16 batches, 8 waves. MFMA columns = batches; one MFMA advances 16
// batches one step:  w' = sel(mask, e^{em_t} ⊙ (E^T w) 2^-BIASF, w).
// Pass 1: wave c runs steps [64c-16, 64(c+1)) from ones -> y_c (dir of alpha).
// Pass 2: wave c (c>=1) runs its own 64 steps from y_{c-1} -> r_c = P_c y_{c-1}.
// Chain:  log2 g_c - log2 g_{c-1} = log2(sum r_c) - log2(sum y_c) + G_c + F_{c-1} - F_c.
__global__ __launch_bounds__(512, 2) void crf_wu(
    const float* __restrict__ em, const int* __restrict__ tg,
    const float* __restrict__ mk, const float* __restrict__ tr,
    float* __restrict__ out)
{
    __shared__ float sY[NW][NB][16];   // pass-1 results [chunk][batch][row]
    __shared__ float sR[NW][NB][16];   // pass-2 results (c>=1)
    __shared__ float sF[NW][NB];       // pass-1 log2 exponents (renorm + BIASF)
    __shared__ float sG[NW][NB];       // pass-2 log2 exponents
    __shared__ float sSc[NB], sCnt[NB], sRes[NB];

    const int tid  = threadIdx.x;
    const int wv   = tid >> 6;
    const int lane = tid & 63;
    const int j    = lane & 15;        // MFMA column = batch-in-block
    const int q    = lane >> 4;        // row-block (rows 4q..4q+3)
    const long gb0 = (long)blockIdx.x * NB;
    const long b   = gb0 + j;          // this lane's batch

    // tags dtype detect (validated): 16 u64 words all <16 => int64 layout
    int is64 = 1;
    {
        const unsigned long long* t64 = (const unsigned long long*)tg;
#pragma unroll
        for (int i = 0; i < 16; ++i) is64 &= (t64[i] < 16ull) ? 1 : 0;
    }
    const int esz = is64 ? 2 : 1;

    // static A = E^T: lane (j,q) holds A[j][4q+i] = exp(tr[4q+i][j])  (validated)
    BF4 Af;
    {
        float Ef[4];
#pragma unroll
        for (int i = 0; i < 4; ++i)
            Ef[i] = exp2f(tr[(q * 4 + i) * 16 + j] * L2E);   // exp(-1000) -> 0
        Af.u[0] = cvt_pk_bf16(Ef[0], Ef[1]);
        Af.u[1] = cvt_pk_bf16(Ef[2], Ef[3]);
    }

    // ---- chain runner: steps [t0, t0+ns) of batch b (r4-validated step math) ----
    auto chain = [&](int t0, int ns, unsigned& p01, unsigned& p23,
                     float& e2f, float& cnt) {
        const float* pe = em + (((long)b * LL + t0) << 4) + (q << 2);
        const float* pm = mk + (long)b * LL + t0;
        f32x4 evc[4], evn[4], mc, mn;
#pragma unroll
        for (int s = 0; s < 4; ++s) evc[s] = *(const f32x4*)(pe + s * 16);
        mc = *(const f32x4*)(pm);
        const int ng = ns >> 2;
        for (int gi = 0; gi < ng; ++gi) {
            const int g = gi << 2;
            if (gi + 1 < ng) {
#pragma unroll
                for (int s = 0; s < 4; ++s)
                    evn[s] = *(const f32x4*)(pe + ((g + 4 + s) << 4));
                mn = *(const f32x4*)(pm + g + 4);
            }
#pragma unroll
            for (int s = 0; s < 4; ++s) {
                const float e0 = exp2f(fmaf(evc[s].x, L2E, -BIASF));
                const float e1 = exp2f(fmaf(evc[s].y, L2E, -BIASF));
                const float e2 = exp2f(fmaf(evc[s].z, L2E, -BIASF));
                const float e3 = exp2f(fmaf(evc[s].w, L2E, -BIASF));
                BF4 Bf; Bf.u[0] = p01; Bf.u[1] = p23;
                f32x4 z = {0.f, 0.f, 0.f, 0.f};
                f32x4 d = __builtin_amdgcn_mfma_f32_16x16x16bf16_1k(Af.s, Bf.s, z, 0, 0, 0);
                const unsigned n01 = cvt_pk_bf16(d[0] * e0, d[1] * e1);
                const unsigned n23 = cvt_pk_bf16(d[2] * e2, d[3] * e3);
                const bool up = mc[s] > 0.f;       // per-column mask select
                p01 = up ? n01 : p01;
                p23 = up ? n23 : p23;
                cnt += mc[s];
            }
            // exact pow2 renorm every 16 steps and at the final group
            if (((gi & 3) == 3) || (gi == ng - 1)) {
                const float v0 = blo(p01), v1 = bhi(p01), v2 = blo(p23), v3 = bhi(p23);
                float mm = fmaxf(fmaxf(v0, v1), fmaxf(v2, v3));
                mm = fmaxf(mm, __shfl_xor(mm, 16));
                mm = fmaxf(mm, __shfl_xor(mm, 32));
                if (mm > 0.f) {
                    const int ex = (int)((__float_as_uint(mm) >> 23) & 0xFFu) - 127;
                    const float sre = __uint_as_float((unsigned)(127 - ex) << 23);
                    e2f += (float)ex;
                    p01 = cvt_pk_bf16(v0 * sre, v1 * sre);
                    p23 = cvt_pk_bf16(v2 * sre, v3 * sre);
                }
            }
            if (gi + 1 < ng) {
#pragma unroll
                for (int s = 0; s < 4; ++s) evc[s] = evn[s];
                mc = mn;
            }
        }
    };

    // ---- pass 1: warmed chunk chains from ones ----
    {
        unsigned p01 = 0x3F803F80u, p23 = 0x3F803F80u;
        float e2f = 0.f, cntc = 0.f;
        const int warm = (wv == 0) ? 0 : WU;
        chain(wv * SS - warm, SS + warm, p01, p23, e2f, cntc);
        sY[wv][j][q * 4 + 0] = blo(p01);
        sY[wv][j][q * 4 + 1] = bhi(p01);
        sY[wv][j][q * 4 + 2] = blo(p23);
        sY[wv][j][q * 4 + 3] = bhi(p23);
        if (lane < 16) sF[wv][j] = e2f + BIASF * cntc;
    }

    // ---- path score + mask count: wave wv handles batches wv, wv+8 ----
#pragma unroll
    for (int h = 0; h < 2; ++h) {
        const int bi = wv + (h << 3);
        const long base = (gb0 + bi) * (long)LL;
        float part = 0.f, cpart = 0.f;
#pragma unroll
        for (int k = 0; k < 8; ++k) {
            const int t = (k << 6) + lane;
            const int tcur = tg[(base + t) * esz];
            const int tpv  = (t == 0) ? START_TAG : (int)tg[(base + t - 1) * esz];
            const float m  = mk[base + t];
            const float scm = (t == 0) ? 1.f : m;
            part = fmaf(em[((base + t) << 4) + tcur] + tr[tpv * 16 + tcur], scm, part);
            cpart += m;
        }
#pragma unroll
        for (int o = 1; o <= 32; o <<= 1) {
            part  += __shfl_xor(part, o);
            cpart += __shfl_xor(cpart, o);
        }
        if (lane == 0) { sSc[bi] = part; sCnt[bi] = cpart; }
    }
    __syncthreads();

    // ---- pass 2: re-run own 64 steps from y_{c-1} (waves 1..7) ----
    if (wv >= 1) {
        const f32x4 y4 = *(const f32x4*)(&sY[wv - 1][j][q * 4]);
        unsigned r01 = cvt_pk_bf16(y4.x, y4.y);
        unsigned r23 = cvt_pk_bf16(y4.z, y4.w);
        float g2f = 0.f, cnt2 = 0.f;
        chain(wv * SS, SS, r01, r23, g2f, cnt2);
        sR[wv][j][q * 4 + 0] = blo(r01);
        sR[wv][j][q * 4 + 1] = bhi(r01);
        sR[wv][j][q * 4 + 2] = blo(r23);
        sR[wv][j][q * 4 + 3] = bhi(r23);
        if (lane < 16) sG[wv][j] = g2f + BIASF * cnt2;
    }
    __syncthreads();

    // ---- combine: 256 threads = 16 batches x 16 components ----
    if (tid < 256) {
        const int bi = tid >> 4, row = tid & 15;
        float x = sY[NW - 1][bi][row] * exp2f(tr[row * 16 + END_TAG] * L2E);
#pragma unroll
        for (int o = 1; o <= 8; o <<= 1) x += __shfl_xor(x, o, 16);
        float l2 = log2f(fmaxf(x, 1e-35f)) + sF[NW - 1][bi];
#pragma unroll
        for (int c2 = 1; c2 < NW; ++c2) {
            float num = sR[c2][bi][row];
            float den = sY[c2][bi][row];
#pragma unroll
            for (int o = 1; o <= 8; o <<= 1) {
                num += __shfl_xor(num, o, 16);
                den += __shfl_xor(den, o, 16);
            }
            l2 += log2f(fmaxf(num, 1e-35f)) - log2f(fmaxf(den, 1e-35f))
                + sG[c2][bi] + sF[c2 - 1][bi] - sF[c2][bi];
        }
        if (row == 0) {
            const float dp = LN2 * l2;
            const int li = (int)sCnt[bi] - 1;
            const int lt = tg[((gb0 + bi) * (long)LL + li) * esz];
            sRes[bi] = dp - (sSc[bi] + tr[lt * 16 + END_TAG]);
        }
    }
    __syncthreads();
    if (tid == 0) {
        float s = 0.f;
#pragma unroll
        for (int i = 0; i < NB; ++i) s += sRes[i];
        atomicAdd(out, s);
    }
}

extern "C" void kernel_launch(void* const* d_in, const int* in_sizes, int n_in,
                              void* d_out, int out_size, void* d_ws, size_t ws_size,
                              hipStream_t stream) {
    const float* em = (const float*)d_in[0];
    const int*   tg = (const int*)d_in[1];
    const float* mk = (const float*)d_in[2];
    const float* tr = (const float*)d_in[3];
    float* out = (float*)d_out;

    hipMemsetAsync(out, 0, sizeof(float), stream);
    crf_wu<<<BS / NB, 512, 0, stream>>>(em, tg, mk, tr, out);
}